// Round 2
// 2492.259 us; speedup vs baseline: 1.2633x; 1.2633x over previous
//
#include <hip/hip_runtime.h>
#include <string.h>

typedef unsigned short ushort_t;

#define NLAYER 3
#define MROWS 2048      // B*L = 4*512
#define DM 512
#define DFF_ 2048
#define VOCAB 32000

__device__ __forceinline__ float b2f(ushort_t u){
  union { unsigned int u; float f; } c; c.u = ((unsigned int)u) << 16; return c.f;
}
__device__ __forceinline__ ushort_t f2b(float f){
  union { float f; unsigned int u; } c; c.f = f;
  unsigned int u = c.u;
  u += 0x7FFFu + ((u >> 16) & 1u);   // RNE
  return (ushort_t)(u >> 16);
}

using bf16x8 = __attribute__((ext_vector_type(8))) short;
using f32x4  = __attribute__((ext_vector_type(4))) float;

typedef const __attribute__((address_space(1))) unsigned int* gas1_t;
typedef __attribute__((address_space(3))) unsigned int* las3_t;
__device__ __forceinline__ void gload16(const void* g, void* l){
  // async global->LDS, 16B/lane; LDS dest = wave-uniform base + lane*16
  __builtin_amdgcn_global_load_lds((gas1_t)g, (las3_t)l, 16, 0, 0);
}

// ---------------- dtype detect: pe[0,0]=0.0, pe[0,1]=1.0 ----------------
__global__ void detect_kernel(const unsigned* __restrict__ pe, int* flag){
  if (threadIdx.x == 0) *flag = (pe[0] != 0u) ? 1 : 0;   // 1 = bf16 storage
}

__device__ __forceinline__ float loadIn(const void* p, size_t i, int isbf){
  return isbf ? b2f(((const ushort_t*)p)[i]) : ((const float*)p)[i];
}

// ---------------- embedding + positional encoding ----------------
__global__ __launch_bounds__(256) void embed_kernel(
    const int* __restrict__ flagp, const int* __restrict__ tok,
    const void* __restrict__ emb, const void* __restrict__ pe,
    float* __restrict__ out)
{
  int isbf = *flagp;
  int row = blockIdx.x, tid = threadIdx.x;
  int t = row & 511;
  int id = tok[row];
  const float scale = 22.62741699796952f;   // sqrt(512)
  #pragma unroll
  for (int i = 0; i < 2; i++){
    int d = tid + i*256;
    float e = loadIn(emb, (size_t)id*DM + d, isbf);
    float p = loadIn(pe,  (size_t)t*DM + d, isbf);
    out[(size_t)row*DM + d] = e * scale + p;
  }
}

// ---------------- layernorm: fp32 in -> bf16 out ----------------
__global__ __launch_bounds__(256) void ln_kernel(
    const int* __restrict__ flagp, const float* __restrict__ x,
    const void* __restrict__ g, size_t goff,
    const void* __restrict__ beta, size_t boff,
    ushort_t* __restrict__ out)
{
  int isbf = *flagp;
  __shared__ float red[8];
  int row = blockIdx.x, tid = threadIdx.x;
  const float* xr = x + (size_t)row*DM;
  float v0 = xr[tid], v1 = xr[tid+256];
  float s = v0 + v1;
  #pragma unroll
  for (int off = 1; off < 64; off <<= 1) s += __shfl_xor(s, off);
  if ((tid & 63) == 0) red[tid >> 6] = s;
  __syncthreads();
  float mean = (red[0]+red[1]+red[2]+red[3]) * (1.f/512.f);
  float d0 = v0 - mean, d1 = v1 - mean;
  float sq = d0*d0 + d1*d1;
  #pragma unroll
  for (int off = 1; off < 64; off <<= 1) sq += __shfl_xor(sq, off);
  if ((tid & 63) == 0) red[4 + (tid >> 6)] = sq;
  __syncthreads();
  float var = (red[4]+red[5]+red[6]+red[7]) * (1.f/512.f);
  float rs = rsqrtf(var + 1e-5f);
  float g0 = loadIn(g, goff + tid, isbf),     g1 = loadIn(g, goff + tid + 256, isbf);
  float b0 = loadIn(beta, boff + tid, isbf),  b1 = loadIn(beta, boff + tid + 256, isbf);
  out[(size_t)row*DM + tid]       = f2b(d0*rs*g0 + b0);
  out[(size_t)row*DM + tid + 256] = f2b(d1*rs*g1 + b1);
}

// ---------------- weight pre-conversion fp32 -> bf16 (no-op if input already bf16) ----
__device__ __forceinline__ void conv_chunk(ushort_t* __restrict__ dst,
                                           const float* __restrict__ src,
                                           int blk, int tid)
{
  size_t o = (size_t)blk*2048 + (size_t)tid*8;
  float4 a = *(const float4*)(src + o);
  float4 b = *(const float4*)(src + o + 4);
  union { ushort_t u[8]; uint4 v; } pk;
  pk.u[0]=f2b(a.x); pk.u[1]=f2b(a.y); pk.u[2]=f2b(a.z); pk.u[3]=f2b(a.w);
  pk.u[4]=f2b(b.x); pk.u[5]=f2b(b.y); pk.u[6]=f2b(b.z); pk.u[7]=f2b(b.w);
  *(uint4*)(dst + o) = pk.v;
}

// 12 attention weight tensors, each 3*512*512 = 786432 elems (384 blocks each)
__global__ __launch_bounds__(256) void conv12_kernel(const int* __restrict__ flagp,
    ushort_t* __restrict__ dst,
    const float* __restrict__ s0, const float* __restrict__ s1,
    const float* __restrict__ s2, const float* __restrict__ s3,
    const float* __restrict__ s4, const float* __restrict__ s5,
    const float* __restrict__ s6, const float* __restrict__ s7,
    const float* __restrict__ s8, const float* __restrict__ s9,
    const float* __restrict__ s10, const float* __restrict__ s11)
{
  if (*flagp) return;
  int t = blockIdx.x / 384;
  int blk = blockIdx.x - t*384;
  const float* s = t==0?s0:t==1?s1:t==2?s2:t==3?s3:t==4?s4:t==5?s5:
                   t==6?s6:t==7?s7:t==8?s8:t==9?s9:t==10?s10:s11;
  conv_chunk(dst + (size_t)t*786432, s, blk, threadIdx.x);
}

// 4 FFN weight tensors, each 3*2048*512 = 3145728 elems (1536 blocks each)
__global__ __launch_bounds__(256) void conv4_kernel(const int* __restrict__ flagp,
    ushort_t* __restrict__ dst,
    const float* __restrict__ s0, const float* __restrict__ s1,
    const float* __restrict__ s2, const float* __restrict__ s3)
{
  if (*flagp) return;
  int t = blockIdx.x / 1536;
  int blk = blockIdx.x - t*1536;
  const float* s = t==0?s0:t==1?s1:t==2?s2:s3;
  conv_chunk(dst + (size_t)t*3145728, s, blk, threadIdx.x);
}

// projW: 32000*512 = 16384000 elems (8000 blocks)
__global__ __launch_bounds__(256) void conv1_kernel(const int* __restrict__ flagp,
    ushort_t* __restrict__ dst, const float* __restrict__ src)
{
  if (*flagp) return;
  conv_chunk(dst, src, blockIdx.x, threadIdx.x);
}

// ---------------- GEMM: C[M,N] = A[M,K](bf16) @ W[N,K]^T + bias ----------------
// Grid = dim3(32, N/64); XCD-chunked swizzle so blocks sharing a W slab run
// consecutively on one XCD (W fetched ~once instead of per-M-tile).
__device__ __forceinline__ void blk_decode(int& bm, int& bn){
  int flat = blockIdx.y * gridDim.x + blockIdx.x;
  int nwg  = gridDim.x * gridDim.y;
  int swz = flat;
  if ((nwg & 7) == 0){
    int cpx = nwg >> 3;
    swz = (flat & 7) * cpx + (flat >> 3);
  }
  bm = swz & 31;          // gridDim.x == 32 always (M = 2048)
  bn = swz >> 5;
}

// bf16-weight path: BK=64, global_load_lds staging, XOR-swizzled LDS
// (swizzle applied via per-lane GLOBAL source address; LDS write is linear).
__device__ __forceinline__ void gemm_body_bf(
    const ushort_t* __restrict__ A, const ushort_t* __restrict__ W,
    const void* __restrict__ bbase, size_t boff, int bisbf,
    const float* __restrict__ resid, void* __restrict__ out,
    int om, int N, int K, int relu, ushort_t* As, ushort_t* Ws)
{
  int tid = threadIdx.x;
  int bm, bn; blk_decode(bm, bn);
  int wave = tid >> 6, lane = tid & 63;
  int wr = wave >> 1, wc = wave & 1;
  f32x4 acc[2][2];
  #pragma unroll
  for (int i=0;i<2;i++)
    #pragma unroll
    for (int j=0;j<2;j++) acc[i][j] = (f32x4){0.f,0.f,0.f,0.f};

  // staging: tile is [64 rows][64 cols] ushort; physical col-slot p holds
  // logical 16B-slot s = p ^ (row&7). gload_lds writes linearly, so lane
  // loads global slot s = (tid&7) ^ ((tid>>3)&7).
  int srow = tid >> 3;
  int scol = (((tid & 7) ^ (srow & 7)) * 8);
  const ushort_t* Ag = A + (size_t)(bm*64 + srow)*K + scol;
  const ushort_t* Wg = W + (size_t)(bn*64 + srow)*K + scol;
  ushort_t* ldsA = As + wave*512;   // wave-uniform; each call = 1KB/wave
  ushort_t* ldsW = Ws + wave*512;

  int fm = lane & 15;
  int xa = fm & 7;
  const ushort_t* Arow0 = &As[(wr*32 + fm)*64];
  const ushort_t* Arow1 = Arow0 + 16*64;
  const ushort_t* Brow0 = &Ws[(wc*32 + fm)*64];
  const ushort_t* Brow1 = Brow0 + 16*64;

  for (int k0 = 0; k0 < K; k0 += 64){
    gload16(Ag + k0,                 ldsA);
    gload16(Ag + (size_t)32*K + k0,  ldsA + 2048);
    gload16(Wg + k0,                 ldsW);
    gload16(Wg + (size_t)32*K + k0,  ldsW + 2048);
    __syncthreads();    // compiler drains vmcnt before s_barrier
    #pragma unroll
    for (int kk = 0; kk < 2; kk++){
      int p8 = (((lane >> 4) + kk*4) ^ xa) * 8;
      bf16x8 a0 = *(const bf16x8*)(Arow0 + p8);
      bf16x8 a1 = *(const bf16x8*)(Arow1 + p8);
      bf16x8 b0 = *(const bf16x8*)(Brow0 + p8);
      bf16x8 b1 = *(const bf16x8*)(Brow1 + p8);
      acc[0][0] = __builtin_amdgcn_mfma_f32_16x16x32_bf16(a0, b0, acc[0][0], 0, 0, 0);
      acc[0][1] = __builtin_amdgcn_mfma_f32_16x16x32_bf16(a0, b1, acc[0][1], 0, 0, 0);
      acc[1][0] = __builtin_amdgcn_mfma_f32_16x16x32_bf16(a1, b0, acc[1][0], 0, 0, 0);
      acc[1][1] = __builtin_amdgcn_mfma_f32_16x16x32_bf16(a1, b1, acc[1][1], 0, 0, 0);
    }
    __syncthreads();
  }
  // C/D layout: row = (lane>>4)*4 + r, col = lane&15  [verified m89/m91]
  int crow = (lane >> 4) * 4;
  int ccol = lane & 15;
  #pragma unroll
  for (int ti = 0; ti < 2; ti++){
    #pragma unroll
    for (int tj = 0; tj < 2; tj++){
      int gm0 = bm*64 + wr*32 + ti*16 + crow;
      int gn  = bn*64 + wc*32 + tj*16 + ccol;
      float bv = bisbf ? b2f(((const ushort_t*)bbase)[boff + gn])
                       : ((const float*)bbase)[boff + gn];
      #pragma unroll
      for (int r = 0; r < 4; r++){
        int gm = gm0 + r;
        size_t idx = (size_t)gm * N + gn;
        float v = acc[ti][tj][r] + bv;
        if (relu) v = fmaxf(v, 0.f);
        if (resid) v += resid[idx];
        if (om) ((ushort_t*)out)[idx] = f2b(v);
        else    ((float*)out)[idx] = v;
      }
    }
  }
}

// fallback fp32-weight path (only if ws too small for the bf16 arena): old BK=32 loop
__device__ __forceinline__ void gemm_body_f32(
    const ushort_t* __restrict__ A, const float* __restrict__ W,
    const void* __restrict__ bbase, size_t boff,
    const float* __restrict__ resid, void* __restrict__ out,
    int om, int N, int K, int relu, ushort_t* As, ushort_t* Ws)
{
  int tid = threadIdx.x;
  int bm, bn; blk_decode(bm, bn);
  int wave = tid >> 6, lane = tid & 63;
  int wr = wave >> 1, wc = wave & 1;
  f32x4 acc[2][2];
  #pragma unroll
  for (int i=0;i<2;i++)
    #pragma unroll
    for (int j=0;j<2;j++) acc[i][j] = (f32x4){0.f,0.f,0.f,0.f};

  int srow = tid >> 2, scol = (tid & 3) * 8;
  const ushort_t* Ag = A + (size_t)(bm*64 + srow)*K + scol;
  const float*    Wg = W + (size_t)(bn*64 + srow)*K + scol;
  ushort_t* AsP = &As[srow*32 + scol];
  ushort_t* WsP = &Ws[srow*32 + scol];
  int fm = lane & 15;
  int fk = (lane >> 4) * 8;
  const ushort_t* ArA = &As[(wr*32 + fm)*32 + fk];
  const ushort_t* WrB = &Ws[(wc*32 + fm)*32 + fk];

  for (int k0 = 0; k0 < K; k0 += 32){
    *(uint4*)AsP = *(const uint4*)(Ag + k0);
    float4 w0 = *(const float4*)(Wg + k0);
    float4 w1 = *(const float4*)(Wg + k0 + 4);
    union { ushort_t u[8]; uint4 v; } pk;
    pk.u[0]=f2b(w0.x); pk.u[1]=f2b(w0.y); pk.u[2]=f2b(w0.z); pk.u[3]=f2b(w0.w);
    pk.u[4]=f2b(w1.x); pk.u[5]=f2b(w1.y); pk.u[6]=f2b(w1.z); pk.u[7]=f2b(w1.w);
    *(uint4*)WsP = pk.v;
    __syncthreads();
    bf16x8 a0 = *(const bf16x8*)(ArA);
    bf16x8 a1 = *(const bf16x8*)(ArA + 16*32);
    bf16x8 b0 = *(const bf16x8*)(WrB);
    bf16x8 b1 = *(const bf16x8*)(WrB + 16*32);
    acc[0][0] = __builtin_amdgcn_mfma_f32_16x16x32_bf16(a0, b0, acc[0][0], 0, 0, 0);
    acc[0][1] = __builtin_amdgcn_mfma_f32_16x16x32_bf16(a0, b1, acc[0][1], 0, 0, 0);
    acc[1][0] = __builtin_amdgcn_mfma_f32_16x16x32_bf16(a1, b0, acc[1][0], 0, 0, 0);
    acc[1][1] = __builtin_amdgcn_mfma_f32_16x16x32_bf16(a1, b1, acc[1][1], 0, 0, 0);
    __syncthreads();
  }
  int crow = (lane >> 4) * 4;
  int ccol = lane & 15;
  #pragma unroll
  for (int ti = 0; ti < 2; ti++){
    #pragma unroll
    for (int tj = 0; tj < 2; tj++){
      int gm0 = bm*64 + wr*32 + ti*16 + crow;
      int gn  = bn*64 + wc*32 + tj*16 + ccol;
      float bv = ((const float*)bbase)[boff + gn];
      #pragma unroll
      for (int r = 0; r < 4; r++){
        int gm = gm0 + r;
        size_t idx = (size_t)gm * N + gn;
        float v = acc[ti][tj][r] + bv;
        if (relu) v = fmaxf(v, 0.f);
        if (resid) v += resid[idx];
        if (om) ((ushort_t*)out)[idx] = f2b(v);
        else    ((float*)out)[idx] = v;
      }
    }
  }
}

// om: 0 = fp32 out, 1 = bf16 out, 2 = input dtype (for d_out)
__global__ __launch_bounds__(256, 2) void gemm_bt(
    const int* __restrict__ flagp, int conv, const ushort_t* __restrict__ A,
    const void* __restrict__ Wbase, size_t woff,
    const ushort_t* __restrict__ Wconv,
    const void* __restrict__ bbase, size_t boff,
    const float* resid, void* out, int om, int N, int K, int relu)
{
  __shared__ __align__(16) ushort_t As[64*64];
  __shared__ __align__(16) ushort_t Ws[64*64];
  int isbf = *flagp;
  if (om == 2) om = isbf;
  if (isbf)
    gemm_body_bf(A, (const ushort_t*)Wbase + woff, bbase, boff, 1, resid, out, om, N, K, relu, As, Ws);
  else if (conv)
    gemm_body_bf(A, Wconv, bbase, boff, 0, resid, out, om, N, K, relu, As, Ws);
  else
    gemm_body_f32(A, (const float*)Wbase + woff, bbase, boff, resid, out, om, N, K, relu, As, Ws);
}

// ---------------- attention: 8 queries per block ----------------
__global__ __launch_bounds__(256) void attn_kernel(
    const float* __restrict__ Q, const float* __restrict__ K,
    const float* __restrict__ V, const int* __restrict__ ktok,
    ushort_t* __restrict__ ctx, int causal)
{
  __shared__ __align__(16) float sQ[8][64];
  __shared__ __align__(16) float sS[8][512];
  __shared__ __align__(16) float sAcc[4][8][64];
  __shared__ float sInv[8];
  int tid = threadIdx.x;
  int blk = blockIdx.x;
  int qg = blk & 63;
  int h  = (blk >> 6) & 7;
  int b  = blk >> 9;
  int q0 = qg * 8;

  #pragma unroll
  for (int i = 0; i < 2; i++){
    int qi = (tid >> 6) + i*4;
    int d  = tid & 63;
    sQ[qi][d] = Q[((size_t)(b*512 + q0 + qi))*DM + h*64 + d];
  }
  __syncthreads();

  float dots[8];
  #pragma unroll
  for (int i = 0; i < 2; i++){
    int k = tid + i*256;
    const float4* K4 = (const float4*)(K + ((size_t)(b*512 + k))*DM + h*64);
    #pragma unroll
    for (int qi = 0; qi < 8; qi++) dots[qi] = 0.f;
    #pragma unroll
    for (int d4 = 0; d4 < 16; d4++){
      float4 kv = K4[d4];
      #pragma unroll
      for (int qi = 0; qi < 8; qi++){
        float4 qv = ((const float4*)sQ)[qi*16 + d4];
        dots[qi] += kv.x*qv.x + kv.y*qv.y + kv.z*qv.z + kv.w*qv.w;
      }
    }
    int pad = (ktok[b*512 + k] == 0);
    #pragma unroll
    for (int qi = 0; qi < 8; qi++){
      bool m = pad || (causal && (k > q0 + qi));
      sS[qi][k] = m ? -1e9f : dots[qi]*0.125f;
    }
  }
  __syncthreads();

  {
    int wv = tid >> 6, ln = tid & 63;
    #pragma unroll
    for (int rr = 0; rr < 2; rr++){
      int r = wv*2 + rr;
      float vals[8];
      float m = -1e30f;
      #pragma unroll
      for (int j = 0; j < 8; j++){ vals[j] = sS[r][j*64 + ln]; m = fmaxf(m, vals[j]); }
      #pragma unroll
      for (int off = 1; off < 64; off <<= 1) m = fmaxf(m, __shfl_xor(m, off));
      float s = 0.f;
      #pragma unroll
      for (int j = 0; j < 8; j++){ vals[j] = __expf(vals[j] - m); s += vals[j]; }
      #pragma unroll
      for (int off = 1; off < 64; off <<= 1) s += __shfl_xor(s, off);
      #pragma unroll
      for (int j = 0; j < 8; j++) sS[r][j*64 + ln] = vals[j];
      if (ln == 0) sInv[r] = 1.f / s;
    }
  }
  __syncthreads();

  {
    int d = tid & 63, kc = tid >> 6;
    float acc[8];
    #pragma unroll
    for (int qi = 0; qi < 8; qi++) acc[qi] = 0.f;
    const float* Vp = V + ((size_t)(b*512 + kc*128))*DM + h*64 + d;
    for (int k4 = 0; k4 < 32; k4++){
      float v0 = Vp[(size_t)(k4*4+0)*DM];
      float v1 = Vp[(size_t)(k4*4+1)*DM];
      float v2 = Vp[(size_t)(k4*4+2)*DM];
      float v3 = Vp[(size_t)(k4*4+3)*DM];
      #pragma unroll
      for (int qi = 0; qi < 8; qi++){
        float4 p = ((const float4*)&sS[qi][kc*128])[k4];
        acc[qi] += p.x*v0 + p.y*v1 + p.z*v2 + p.w*v3;
      }
    }
    #pragma unroll
    for (int qi = 0; qi < 8; qi++) sAcc[kc][qi][d] = acc[qi];
  }
  __syncthreads();

  #pragma unroll
  for (int i = 0; i < 2; i++){
    int o = tid + i*256;
    int qi = o >> 6, d = o & 63;
    float v = (sAcc[0][qi][d] + sAcc[1][qi][d] + sAcc[2][qi][d] + sAcc[3][qi][d]) * sInv[qi];
    ctx[((size_t)(b*512 + q0 + qi))*DM + h*64 + d] = f2b(v);
  }
}

// ---------------- elementwise helpers ----------------
__global__ __launch_bounds__(256) void add_kernel(float* a, const float* __restrict__ b, int n){
  int i = blockIdx.x*256 + threadIdx.x;
  if (i < n) a[i] += b[i];
}
__global__ __launch_bounds__(256) void tob16_kernel(const float* __restrict__ a, ushort_t* __restrict__ o, int n){
  int i = blockIdx.x*256 + threadIdx.x;
  if (i < n) o[i] = f2b(a[i]);
}

// ---------------- host ----------------
extern "C" void kernel_launch(void* const* d_in, const int* in_sizes, int n_in,
                              void* d_out, int out_size, void* d_ws, size_t ws_size,
                              hipStream_t stream)
{
  const int* enc_in = (const int*)d_in[0];
  const int* dec_in = (const int*)d_in[1];

  char* ws = (char*)d_ws;
  float*    xf   = (float*)(ws);                 // 4 MB  residual stream (fp32)
  float*    qf   = (float*)(ws + (4u<<20));      // 4 MB
  float*    kf   = (float*)(ws + (8u<<20));      // 4 MB
  float*    vf   = (float*)(ws + (12u<<20));     // 4 MB
  float*    caf  = (float*)(ws + (16u<<20));     // 4 MB  cross-attn output
  ushort_t* hb   = (ushort_t*)(ws + (20u<<20));  // 2 MB  bf16 LN out
  ushort_t* ctxb = (ushort_t*)(ws + (22u<<20));  // 2 MB  bf16 attn ctx
  ushort_t* ffb  = (ushort_t*)(ws + (24u<<20));  // 8 MB  bf16 ffn hidden
  ushort_t* encb = (ushort_t*)(ws + (32u<<20));  // 2 MB  bf16 encoder out
  ushort_t* yb   = (ushort_t*)(ws + (34u<<20));  // 2 MB  bf16 final y
  int*      flagp= (int*)(ws + (36u<<20));       // dtype flag

  // bf16 weight arena at 40 MB
  const size_t ATT_T  = 786432ull;    // 3*512*512
  const size_t FFN_T  = 3145728ull;   // 3*2048*512
  const size_t PROJ_T = 16384000ull;  // 32000*512
  const size_t LW     = 262144ull;    // 512*512 per layer
  const size_t LF     = 1048576ull;   // 2048*512 per layer
  const size_t need = (40ull<<20) + 2ull*(12*ATT_T + 4*FFN_T + PROJ_T);
  int conv = (ws_size >= need) ? 1 : 0;
  ushort_t* uw    = (ushort_t*)(ws + (40u<<20));
  ushort_t* wATT  = uw;
  ushort_t* wFFN  = uw + 12*ATT_T;
  ushort_t* wPROJ = wFFN + 4*FFN_T;

  detect_kernel<<<1, 64, 0, stream>>>((const unsigned*)d_in[4], flagp);

  auto F = [&](int i){ return (const float*)d_in[i]; };
  if (conv){
    conv12_kernel<<<4608, 256, 0, stream>>>(flagp, wATT,
        F(5), F(7), F(9), F(11), F(13), F(15), F(17), F(19), F(21), F(23), F(25), F(27));
    conv4_kernel<<<6144, 256, 0, stream>>>(flagp, wFFN, F(29), F(31), F(33), F(35));
    conv1_kernel<<<8000, 256, 0, stream>>>(flagp, wPROJ, F(49));
  }

  auto GEMM = [&](const void* A, int wi, size_t wo, const ushort_t* wc,
                  int bi, size_t bo, const float* resid, void* out, int om,
                  int N, int Kd, int relu){
    gemm_bt<<<dim3(32, N/64), 256, 0, stream>>>(flagp, conv, (const ushort_t*)A,
        d_in[wi], wo, wc, d_in[bi], bo, resid, out, om, N, Kd, relu);
  };
  auto LN = [&](const float* x, int gi, size_t go, int bi, size_t bo, ushort_t* o){
    ln_kernel<<<MROWS, 256, 0, stream>>>(flagp, x, d_in[gi], go, d_in[bi], bo, o);
  };
  const int NELT = MROWS * DM;   // 1M

  // ======== encoder ========
  embed_kernel<<<MROWS, 256, 0, stream>>>(flagp, enc_in, d_in[2], d_in[4], xf);
  for (int l = 0; l < NLAYER; l++){
    size_t wo = (size_t)l*LW, bo = (size_t)l*DM;
    size_t f1o = (size_t)l*LF, f1bo = (size_t)l*DFF_;
    LN(xf, 37, bo, 38, bo, hb);
    GEMM(hb, 5, wo, wATT + 0*ATT_T + l*LW, 6,  bo, nullptr, qf, 0, DM, DM, 0);
    GEMM(hb, 7, wo, wATT + 1*ATT_T + l*LW, 8,  bo, nullptr, kf, 0, DM, DM, 0);
    GEMM(hb, 9, wo, wATT + 2*ATT_T + l*LW, 10, bo, nullptr, vf, 0, DM, DM, 0);
    attn_kernel<<<2048, 256, 0, stream>>>(qf, kf, vf, enc_in, ctxb, 0);
    GEMM(ctxb, 11, wo, wATT + 3*ATT_T + l*LW, 12, bo, xf, xf, 0, DM, DM, 0);
    LN(xf, 39, bo, 40, bo, hb);
    GEMM(hb, 29, f1o, wFFN + 0*FFN_T + l*LF, 30, f1bo, nullptr, ffb, 1, DFF_, DM, 1);
    GEMM(ffb, 31, f1o, wFFN + 1*FFN_T + l*LF, 32, bo, xf, xf, 0, DM, DFF_, 0);
  }
  LN(xf, 47, 0, 48, 0, encb);

  // ======== decoder ========
  embed_kernel<<<MROWS, 256, 0, stream>>>(flagp, dec_in, d_in[3], d_in[4], xf);
  for (int l = 0; l < NLAYER; l++){
    size_t wo = (size_t)l*LW, bo = (size_t)l*DM;
    size_t f1o = (size_t)l*LF, f1bo = (size_t)l*DFF_;
    // self-attn (causal + dec pad)
    LN(xf, 41, bo, 42, bo, hb);
    GEMM(hb, 13, wo, wATT + 4*ATT_T + l*LW, 14, bo, nullptr, qf, 0, DM, DM, 0);
    GEMM(hb, 15, wo, wATT + 5*ATT_T + l*LW, 16, bo, nullptr, kf, 0, DM, DM, 0);
    GEMM(hb, 17, wo, wATT + 6*ATT_T + l*LW, 18, bo, nullptr, vf, 0, DM, DM, 0);
    attn_kernel<<<2048, 256, 0, stream>>>(qf, kf, vf, dec_in, ctxb, 1);
    GEMM(ctxb, 19, wo, wATT + 7*ATT_T + l*LW, 20, bo, xf, xf, 0, DM, DM, 0);
    // cross-attn (enc pad, K/V from encoder output)
    LN(xf, 43, bo, 44, bo, hb);
    GEMM(hb,   21, wo, wATT + 8*ATT_T  + l*LW, 22, bo, nullptr, qf, 0, DM, DM, 0);
    GEMM(encb, 23, wo, wATT + 9*ATT_T  + l*LW, 24, bo, nullptr, kf, 0, DM, DM, 0);
    GEMM(encb, 25, wo, wATT + 10*ATT_T + l*LW, 26, bo, nullptr, vf, 0, DM, DM, 0);
    attn_kernel<<<2048, 256, 0, stream>>>(qf, kf, vf, enc_in, ctxb, 0);
    GEMM(ctxb, 27, wo, wATT + 11*ATT_T + l*LW, 28, bo, nullptr, caf, 0, DM, DM, 0);
    add_kernel<<<NELT/256, 256, 0, stream>>>(xf, caf, NELT);   // y = y + ca
    // ffn with residual = ca
    LN(xf, 45, bo, 46, bo, hb);
    GEMM(hb, 33, f1o, wFFN + 2*FFN_T + l*LF, 34, f1bo, nullptr, ffb, 1, DFF_, DM, 1);
    GEMM(ffb, 35, f1o, wFFN + 3*FFN_T + l*LF, 36, bo, caf, xf, 0, DM, DFF_, 0);
  }

  // ======== final projection (output in input dtype) ========
  tob16_kernel<<<NELT/256, 256, 0, stream>>>(xf, yb, NELT);
  GEMM(yb, 49, 0, wPROJ, 50, 0, nullptr, d_out, 2, VOCAB, DM, 0);
}